// Round 2
// baseline (684.512 us; speedup 1.0000x reference)
//
#include <hip/hip_runtime.h>

#define IN_DIM 512
#define OUT_DIM 16
#define KC 32
#define TILE_ROWS 256

// ---------------------------------------------------------------------------
// h = x @ W  (n x 512) @ (512 x 16) -> (n x 16), fp32 vector ALU.
// x staged through LDS in 256-row x 32-col tiles (pad +1: <=2-way bank alias,
// free). W row loads are wave-uniform -> scalar cache. HBM-bound on x read.
// ---------------------------------------------------------------------------
__global__ __launch_bounds__(256) void gemm_xw(const float* __restrict__ x,
                                               const float* __restrict__ W,
                                               float* __restrict__ h, int n) {
    __shared__ float xs[TILE_ROWS * (KC + 1)];
    const int tid = threadIdx.x;
    const int rbase = blockIdx.x * TILE_ROWS;
    const int myrow = rbase + tid;

    float acc[OUT_DIM];
#pragma unroll
    for (int j = 0; j < OUT_DIM; ++j) acc[j] = 0.f;

    for (int kc = 0; kc < IN_DIM; kc += KC) {
        __syncthreads();
        // cooperative coalesced load: tile rows [rbase, rbase+256) cols [kc, kc+KC)
        // 2048 float4s total, 8 per thread.
#pragma unroll
        for (int i = 0; i < 8; ++i) {
            const int v = tid + 256 * i;   // float4 index within tile
            const int r = v >> 3;          // row within tile
            const int c = (v & 7) << 2;    // col (floats) within tile
            if (rbase + r < n) {
                const float4 f = *(const float4*)(x + (size_t)(rbase + r) * IN_DIM + kc + c);
                float* d = xs + r * (KC + 1) + c;
                d[0] = f.x; d[1] = f.y; d[2] = f.z; d[3] = f.w;
            }
        }
        __syncthreads();

        const float* xrow = xs + tid * (KC + 1);
#pragma unroll 4
        for (int k = 0; k < KC; ++k) {
            const float xv = xrow[k];
            const float* wr = W + (size_t)(kc + k) * OUT_DIM;  // uniform address -> s_load
            const float4 w0 = *(const float4*)(wr + 0);
            const float4 w1 = *(const float4*)(wr + 4);
            const float4 w2 = *(const float4*)(wr + 8);
            const float4 w3 = *(const float4*)(wr + 12);
            acc[0]  += xv * w0.x; acc[1]  += xv * w0.y; acc[2]  += xv * w0.z; acc[3]  += xv * w0.w;
            acc[4]  += xv * w1.x; acc[5]  += xv * w1.y; acc[6]  += xv * w1.z; acc[7]  += xv * w1.w;
            acc[8]  += xv * w2.x; acc[9]  += xv * w2.y; acc[10] += xv * w2.z; acc[11] += xv * w2.w;
            acc[12] += xv * w3.x; acc[13] += xv * w3.y; acc[14] += xv * w3.z; acc[15] += xv * w3.w;
        }
    }

    if (myrow < n) {
        float4* op = (float4*)(h + (size_t)myrow * OUT_DIM);
        op[0] = make_float4(acc[0],  acc[1],  acc[2],  acc[3]);
        op[1] = make_float4(acc[4],  acc[5],  acc[6],  acc[7]);
        op[2] = make_float4(acc[8],  acc[9],  acc[10], acc[11]);
        op[3] = make_float4(acc[12], acc[13], acc[14], acc[15]);
    }
}

// deg[i] = 1.0 (self-loop) -- also serves as ws init since ws is poisoned.
__global__ void deg_init(float* __restrict__ deg, int n) {
    const int i = blockIdx.x * 256 + threadIdx.x;
    if (i < n) deg[i] = 1.0f;
}

// deg[col[e]] += 1 over all edges (col = targets = edge_index[1]).
__global__ void deg_count(const int* __restrict__ col, float* __restrict__ deg, int E) {
    const int e = blockIdx.x * 256 + threadIdx.x;
    if (e < E) atomicAdd(&deg[col[e]], 1.0f);
}

// dinv[i] = rsqrt(deg[i]); out[i][j] = dinv[i]^2 * h[i][j] + b[j]  (self-loop + bias)
// Also initializes the poisoned d_out.
__global__ void dinv_out_init(const float* __restrict__ deg, float* __restrict__ dinv,
                              const float* __restrict__ h, const float* __restrict__ b,
                              float* __restrict__ out, int n) {
    const int gid = blockIdx.x * 256 + threadIdx.x;
    if (gid >= n * OUT_DIM) return;
    const int i = gid >> 4;
    const int j = gid & 15;
    const float di = rsqrtf(deg[i]);
    if (j == 0) dinv[i] = di;
    out[gid] = di * di * h[gid] + b[j];
}

// For each edge (src -> dst): out[dst] += dinv[src]*dinv[dst] * h[src]
// 16 lanes per edge: h-gather and out-atomics are 64B-contiguous per edge.
__global__ __launch_bounds__(256) void edge_scatter(const int* __restrict__ ei,
                                                    const float* __restrict__ dinv,
                                                    const float* __restrict__ h,
                                                    float* __restrict__ out, int E) {
    const int t = blockIdx.x * 256 + threadIdx.x;
    const int e = t >> 4;
    if (e >= E) return;
    const int j = t & 15;
    const int src = ei[e];
    const int dst = ei[(size_t)E + e];
    const float a = dinv[src] * dinv[dst];
    atomicAdd(&out[(size_t)dst * OUT_DIM + j], a * h[(size_t)src * OUT_DIM + j]);
}

extern "C" void kernel_launch(void* const* d_in, const int* in_sizes, int n_in,
                              void* d_out, int out_size, void* d_ws, size_t ws_size,
                              hipStream_t stream) {
    const float* x  = (const float*)d_in[0];
    const int*   ei = (const int*)d_in[1];     // int inputs delivered as int32!
    const float* W  = (const float*)d_in[2];
    const float* b  = (const float*)d_in[3];
    float* out = (float*)d_out;

    const int n = in_sizes[0] / IN_DIM;   // 100000
    const int E = in_sizes[1] / 2;        // 3200000

    // workspace layout: h [n*16] | deg [n] | dinv [n]
    float* h    = (float*)d_ws;
    float* deg  = h + (size_t)n * OUT_DIM;
    float* dinv = deg + n;

    const int gemm_blocks = (n + TILE_ROWS - 1) / TILE_ROWS;
    gemm_xw<<<gemm_blocks, 256, 0, stream>>>(x, W, h, n);

    deg_init<<<(n + 255) / 256, 256, 0, stream>>>(deg, n);
    deg_count<<<(E + 255) / 256, 256, 0, stream>>>(ei + E, deg, E);

    dinv_out_init<<<((n * OUT_DIM) + 255) / 256, 256, 0, stream>>>(deg, dinv, h, b, out, n);

    const long long scatter_threads = (long long)E * OUT_DIM;
    const int scatter_blocks = (int)((scatter_threads + 255) / 256);
    edge_scatter<<<scatter_blocks, 256, 0, stream>>>(ei, dinv, h, out, E);
}